// Round 7
// baseline (568.499 us; speedup 1.0000x reference)
//
#include <hip/hip_runtime.h>
#include <hip/hip_cooperative_groups.h>
#include <math.h>

namespace cg = cooperative_groups;

#define D 96
#define RSQ 0.10206207261596577f  // 1/sqrt(96)
#define TSTRIDE 104               // padded LDS row stride (bf16 elems)

typedef __attribute__((ext_vector_type(8))) short short8;
typedef __attribute__((ext_vector_type(4))) float f32x4;

__device__ __forceinline__ unsigned short f2bf(float f){
  unsigned u = __float_as_uint(f);
  unsigned r = (u + 0x7fff + ((u >> 16) & 1)) >> 16;  // RNE
  return (unsigned short)r;
}
__device__ __forceinline__ float bf2f(unsigned short h){
  return __uint_as_float(((unsigned)h) << 16);
}
__device__ __forceinline__ float bflo(unsigned u){ return __uint_as_float(u << 16); }
__device__ __forceinline__ float bfhi(unsigned u){ return __uint_as_float(u & 0xffff0000u); }
__device__ __forceinline__ int lbound(const int* __restrict__ a, int n, int v){
  int lo = 0, hi = n;
  while (lo < hi){ int mid = (lo + hi) >> 1; if (a[mid] < v) lo = mid + 1; else hi = mid; }
  return lo;
}

struct BuildArgs {
  const float* x;
  const float *w1, *b1, *w2, *b2, *w3, *b3, *w4, *b4, *w5, *b5;
  const int *srcI, *dstI;
  const float* eattr;
  unsigned short *wt_h, *wt_l;
  float* acc_o; unsigned short* x2o; float* x3o; unsigned short* x4o;
  float *p5, *pb;
  int *deg, *fill, *rowp, *partials;
  int2* sortedSE;
  int N, E, NB, NT;
};

// ---- phase bodies, shared by coop kernel and fallback kernels ----

__device__ __forceinline__ void do_wprep(const BuildArgs& A, int gtid, int gstride){
  for (int idx = gtid; idx < 4 * D * D; idx += gstride){
    int m = idx / (D * D);
    int r = idx % (D * D);
    int nn = r / D, k = r % D;
    const float* w = (m == 0) ? A.w1 : (m == 1) ? A.w2 : (m == 2) ? A.w3 : A.w4;
    float v = w[k * D + nn];
    unsigned short h = f2bf(v);
    A.wt_h[idx] = h;
    A.wt_l[idx] = f2bf(v - bf2f(h));
  }
}

__device__ __forceinline__ void do_deg(const BuildArgs& A, int gtid, int gstride){
  for (int e = gtid; e < A.E; e += gstride) atomicAdd(&A.deg[A.dstI[e]], 1);
}

__device__ __forceinline__ void do_transform(const BuildArgs& A,
    unsigned short (*xs_h)[TSTRIDE], unsigned short (*xs_l)[TSTRIDE],
    int tile0, int tstride){
  int tid = threadIdx.x;
  int lane = tid & 63;
  int wv = tid >> 6;
  int lr = lane & 15;
  int kg = lane >> 4;
  const unsigned short* wtm_h = A.wt_h + (size_t)wv * D * D;
  const unsigned short* wtm_l = A.wt_l + (size_t)wv * D * D;
  const float* bias = (wv == 0) ? A.b1 : (wv == 1) ? A.b2 : (wv == 2) ? A.b3 : A.b4;
  for (int tile = tile0; tile < A.NT; tile += tstride){
    int n0 = tile * 16;
    for (int e = tid; e < 16 * D; e += 256){
      int r = e / D, c = e % D;
      int node = n0 + r;
      float v = (node < A.N) ? A.x[(size_t)node * D + c] : 0.0f;
      unsigned short h = f2bf(v);
      xs_h[r][c] = h;
      xs_l[r][c] = f2bf(v - bf2f(h));
    }
    __syncthreads();

    f32x4 acc0 = {0,0,0,0}, acc1 = {0,0,0,0}, acc2 = {0,0,0,0};
    f32x4 acc3 = {0,0,0,0}, acc4 = {0,0,0,0}, acc5 = {0,0,0,0};
    #pragma unroll
    for (int k0 = 0; k0 < D; k0 += 32){
      int kb = k0 + kg * 8;
      short8 ah = *(const short8*)&xs_h[lr][kb];
      short8 al = *(const short8*)&xs_l[lr][kb];
      #pragma unroll
      for (int nc = 0; nc < 6; ++nc){
        int col = nc * 16 + lr;
        short8 bh = *(const short8*)(wtm_h + col * D + kb);
        short8 bl = *(const short8*)(wtm_l + col * D + kb);
        f32x4 a = (nc == 0) ? acc0 : (nc == 1) ? acc1 : (nc == 2) ? acc2
                : (nc == 3) ? acc3 : (nc == 4) ? acc4 : acc5;
        a = __builtin_amdgcn_mfma_f32_16x16x32_bf16(ah, bh, a, 0, 0, 0);
        a = __builtin_amdgcn_mfma_f32_16x16x32_bf16(ah, bl, a, 0, 0, 0);
        a = __builtin_amdgcn_mfma_f32_16x16x32_bf16(al, bh, a, 0, 0, 0);
        if (nc == 0) acc0 = a; else if (nc == 1) acc1 = a; else if (nc == 2) acc2 = a;
        else if (nc == 3) acc3 = a; else if (nc == 4) acc4 = a; else acc5 = a;
      }
    }

    float p5p0 = 0, p5p1 = 0, p5p2 = 0, p5p3 = 0;
    float pbp0 = 0, pbp1 = 0, pbp2 = 0, pbp3 = 0;
    #pragma unroll
    for (int nc = 0; nc < 6; ++nc){
      int col = nc * 16 + lr;
      float bb = bias[col];
      float w5v = A.w5[col], b5v = A.b5[col];
      f32x4 a = (nc == 0) ? acc0 : (nc == 1) ? acc1 : (nc == 2) ? acc2
              : (nc == 3) ? acc3 : (nc == 4) ? acc4 : acc5;
      #pragma unroll
      for (int q = 0; q < 4; ++q){
        float v = a[q] + bb;
        int row = kg * 4 + q;
        if (n0 + row < A.N){
          size_t o = (size_t)(n0 + row) * D + col;
          if (wv == 0) A.acc_o[o] = v;
          else if (wv == 1) A.x2o[o] = f2bf(v);
          else if (wv == 2) A.x3o[o] = v;
          else A.x4o[o] = f2bf(v);
        }
        float t5 = v * w5v, tb = v * b5v;
        if (q == 0){ p5p0 += t5; pbp0 += tb; }
        else if (q == 1){ p5p1 += t5; pbp1 += tb; }
        else if (q == 2){ p5p2 += t5; pbp2 += tb; }
        else { p5p3 += t5; pbp3 += tb; }
      }
    }
    if (wv == 2){
      #pragma unroll
      for (int off = 1; off < 16; off <<= 1){
        p5p0 += __shfl_xor(p5p0, off); pbp0 += __shfl_xor(pbp0, off);
        p5p1 += __shfl_xor(p5p1, off); pbp1 += __shfl_xor(pbp1, off);
        p5p2 += __shfl_xor(p5p2, off); pbp2 += __shfl_xor(pbp2, off);
        p5p3 += __shfl_xor(p5p3, off); pbp3 += __shfl_xor(pbp3, off);
      }
      if (lr == 0){
        int row = kg * 4;
        if (n0 + row < A.N)     { A.p5[n0 + row]     = p5p0; A.pb[n0 + row]     = pbp0; }
        if (n0 + row + 1 < A.N) { A.p5[n0 + row + 1] = p5p1; A.pb[n0 + row + 1] = pbp1; }
        if (n0 + row + 2 < A.N) { A.p5[n0 + row + 2] = p5p2; A.pb[n0 + row + 2] = pbp2; }
        if (n0 + row + 3 < A.N) { A.p5[n0 + row + 3] = p5p3; A.pb[n0 + row + 3] = pbp3; }
      }
    }
    __syncthreads();  // protect xs before next tile's stage
  }
}

__device__ __forceinline__ void do_scanA(const BuildArgs& A, int* ws,
                                         int chunk0, int cstride){
  int tid = threadIdx.x, lane = tid & 63, wid = tid >> 6;
  for (int chunk = chunk0; chunk < A.NB; chunk += cstride){
    int i = chunk * 256 + tid;
    int v = (i < A.N) ? A.deg[i] : 0;
    int s = v;
    #pragma unroll
    for (int off = 1; off < 64; off <<= 1){ int u = __shfl_up(s, off); if (lane >= off) s += u; }
    if (lane == 63) ws[wid] = s;
    __syncthreads();
    if (tid < 4){
      int u = ws[tid];
      #pragma unroll
      for (int off = 1; off < 4; off <<= 1){ int q = __shfl_up(u, off); if (tid >= off) u += q; }
      ws[tid] = u;
    }
    __syncthreads();
    int woff = wid ? ws[wid - 1] : 0;
    if (i < A.N) A.rowp[i] = woff + s - v;
    if (tid == 255) A.partials[chunk] = ws[3];
    __syncthreads();
  }
}

__device__ __forceinline__ void do_scanB(const BuildArgs& A, int* ws){
  int tid = threadIdx.x, lane = tid & 63, wid = tid >> 6;
  int running = 0;
  for (int base = 0; base < A.NB; base += 256){
    int i = base + tid;
    int v = (i < A.NB) ? A.partials[i] : 0;
    int s = v;
    #pragma unroll
    for (int off = 1; off < 64; off <<= 1){ int u = __shfl_up(s, off); if (lane >= off) s += u; }
    if (lane == 63) ws[wid] = s;
    __syncthreads();
    if (tid < 4){
      int u = ws[tid];
      #pragma unroll
      for (int off = 1; off < 4; off <<= 1){ int q = __shfl_up(u, off); if (tid >= off) u += q; }
      ws[tid] = u;
    }
    __syncthreads();
    int woff = wid ? ws[wid - 1] : 0;
    if (i < A.NB) A.partials[i] = running + woff + s - v;
    running += ws[3];
    __syncthreads();
  }
  if (tid == 0) A.rowp[A.N] = running;
}

__device__ __forceinline__ void do_scatter(const BuildArgs& A, int gtid, int gstride){
  for (int e = gtid; e < A.E; e += gstride){
    int t = A.dstI[e];
    int pos = A.rowp[t] + A.partials[t >> 8] + atomicAdd(&A.fill[t], 1);
    A.sortedSE[pos] = make_int2(A.srcI[e], __float_as_int(A.eattr[e]));
  }
}

// ---- cooperative mega-kernel (512 blocks => only 2 blocks/CU needed) ----
__global__ __launch_bounds__(256, 2) void k_build(BuildArgs A){
  cg::grid_group grid = cg::this_grid();
  __shared__ __align__(16) unsigned short xs_h[16][TSTRIDE];
  __shared__ __align__(16) unsigned short xs_l[16][TSTRIDE];
  __shared__ int ws[4];
  int tid = threadIdx.x;
  int gtid = blockIdx.x * 256 + tid;
  int gstride = gridDim.x * 256;

  do_wprep(A, gtid, gstride);
  do_deg(A, gtid, gstride);
  grid.sync();
  do_transform(A, xs_h, xs_l, blockIdx.x, gridDim.x);
  do_scanA(A, ws, blockIdx.x, gridDim.x);
  grid.sync();
  if (blockIdx.x == 0) do_scanB(A, ws);
  grid.sync();
  do_scatter(A, gtid, gstride);
}

// ---- fallback kernels (used only if the cooperative launch is rejected) ----
__global__ __launch_bounds__(256) void k_wprep_deg(BuildArgs A){
  int gtid = blockIdx.x * 256 + threadIdx.x, gstride = gridDim.x * 256;
  do_wprep(A, gtid, gstride);
  do_deg(A, gtid, gstride);
}
__global__ __launch_bounds__(256) void k_transform_sep(BuildArgs A){
  __shared__ __align__(16) unsigned short xs_h[16][TSTRIDE];
  __shared__ __align__(16) unsigned short xs_l[16][TSTRIDE];
  do_transform(A, xs_h, xs_l, blockIdx.x, gridDim.x);
}
__global__ __launch_bounds__(256) void k_scanA_sep(BuildArgs A){
  __shared__ int ws[4];
  do_scanA(A, ws, blockIdx.x, gridDim.x);
}
__global__ __launch_bounds__(256) void k_scanB_sep(BuildArgs A){
  __shared__ int ws[4];
  do_scanB(A, ws);
}
__global__ __launch_bounds__(256) void k_scatter_sep(BuildArgs A){
  int gtid = blockIdx.x * 256 + threadIdx.x, gstride = gridDim.x * 256;
  do_scatter(A, gtid, gstride);
}

// k_attn: fused attention per dst row — one wave per node, 16 lanes per edge,
// 8 edges in flight (2×4 unroll); bf16 gathers; online softmax.
__global__ __launch_bounds__(256) void k_attn(
    const unsigned short* __restrict__ x2b, const float* __restrict__ x3,
    const unsigned short* __restrict__ x4b, const float* __restrict__ p5,
    const float* __restrict__ pb, const int2* __restrict__ sortedSE,
    const int* __restrict__ rowp, const int* __restrict__ partials,
    float* __restrict__ node_acc, int n){
  int t = blockIdx.x * 4 + (threadIdx.x >> 6);
  int lane = threadIdx.x & 63;
  if (t >= n) return;
  int beg = rowp[t] + partials[t >> 8];
  int end = (t + 1 < n) ? (rowp[t + 1] + partials[(t + 1) >> 8]) : rowp[n];
  if (beg == end) return;
  int j = lane & 15;
  int g = lane >> 4;

  const float2* r3 = (const float2*)(x3 + (size_t)t * D);
  float2 v0 = r3[j], v1 = r3[j + 16], v2 = r3[j + 32];
  float p5t = p5[t], pbt = pb[t];

  float m = -INFINITY, dsum = 0.0f;
  float a0 = 0, a1 = 0, a2 = 0, a3 = 0, a4 = 0, a5 = 0;

  for (int c = beg; c < end; c += 8){
    int eA = c + g, eB = c + 4 + g;
    bool actA = eA < end, actB = eB < end;
    int2 seA = sortedSE[actA ? eA : end - 1];
    int2 seB = sortedSE[actB ? eB : end - 1];
    const unsigned* r4A = (const unsigned*)(x4b + (size_t)seA.x * D);
    const unsigned* r4B = (const unsigned*)(x4b + (size_t)seB.x * D);
    unsigned uA0 = r4A[j], uA1 = r4A[j + 16], uA2 = r4A[j + 32];
    unsigned uB0 = r4B[j], uB1 = r4B[j + 16], uB2 = r4B[j + 32];
    float sA = v0.x * bflo(uA0) + v0.y * bfhi(uA0)
             + v1.x * bflo(uA1) + v1.y * bfhi(uA1)
             + v2.x * bflo(uA2) + v2.y * bfhi(uA2);
    float sB = v0.x * bflo(uB0) + v0.y * bfhi(uB0)
             + v1.x * bflo(uB1) + v1.y * bfhi(uB1)
             + v2.x * bflo(uB2) + v2.y * bfhi(uB2);
    sA += __shfl_xor(sA, 1); sA += __shfl_xor(sA, 2);
    sA += __shfl_xor(sA, 4); sA += __shfl_xor(sA, 8);
    sB += __shfl_xor(sB, 1); sB += __shfl_xor(sB, 2);
    sB += __shfl_xor(sB, 4); sB += __shfl_xor(sB, 8);
    float scA = actA ? (sA + __int_as_float(seA.y) * p5t + pbt) * RSQ : -INFINITY;
    float scB = actB ? (sB + __int_as_float(seB.y) * p5t + pbt) * RSQ : -INFINITY;
    float mc = fmaxf(scA, scB);
    mc = fmaxf(mc, __shfl_xor(mc, 16));
    mc = fmaxf(mc, __shfl_xor(mc, 32));
    if (mc > m){
      float r = __expf(m - mc);   // 0 on first iteration (m = -inf)
      dsum *= r; a0 *= r; a1 *= r; a2 *= r; a3 *= r; a4 *= r; a5 *= r;
      m = mc;
    }
    float wA = __expf(scA - m);   // 0 for inactive
    float wB = __expf(scB - m);
    dsum += wA + wB;
    const unsigned* r2A = (const unsigned*)(x2b + (size_t)seA.x * D);
    const unsigned* r2B = (const unsigned*)(x2b + (size_t)seB.x * D);
    unsigned qA0 = r2A[j], qA1 = r2A[j + 16], qA2 = r2A[j + 32];
    unsigned qB0 = r2B[j], qB1 = r2B[j + 16], qB2 = r2B[j + 32];
    a0 += wA * bflo(qA0) + wB * bflo(qB0);
    a1 += wA * bfhi(qA0) + wB * bfhi(qB0);
    a2 += wA * bflo(qA1) + wB * bflo(qB1);
    a3 += wA * bfhi(qA1) + wB * bfhi(qB1);
    a4 += wA * bflo(qA2) + wB * bflo(qB2);
    a5 += wA * bfhi(qA2) + wB * bfhi(qB2);
  }
  a0 += __shfl_xor(a0, 16); a0 += __shfl_xor(a0, 32);
  a1 += __shfl_xor(a1, 16); a1 += __shfl_xor(a1, 32);
  a2 += __shfl_xor(a2, 16); a2 += __shfl_xor(a2, 32);
  a3 += __shfl_xor(a3, 16); a3 += __shfl_xor(a3, 32);
  a4 += __shfl_xor(a4, 16); a4 += __shfl_xor(a4, 32);
  a5 += __shfl_xor(a5, 16); a5 += __shfl_xor(a5, 32);
  dsum += __shfl_xor(dsum, 16); dsum += __shfl_xor(dsum, 32);
  float inv = 1.0f / (dsum + 1e-16f);
  if (lane < 16){
    size_t o = (size_t)t * D + 2 * j;
    node_acc[o]      += a0 * inv;
    node_acc[o + 1]  += a1 * inv;
    node_acc[o + 32] += a2 * inv;
    node_acc[o + 33] += a3 * inv;
    node_acc[o + 64] += a4 * inv;
    node_acc[o + 65] += a5 * inv;
  }
}

// k_pool: per-graph partial sums + fused finalization (last-chunk ticket).
__global__ __launch_bounds__(96) void k_pool(
    const float* __restrict__ node_out, const int* __restrict__ batch,
    float* __restrict__ sums, int* __restrict__ gdone,
    float* __restrict__ out, int n){
  int g = blockIdx.x;
  int chunk = blockIdx.y, nch = gridDim.y;
  int d = threadIdx.x;
  int lo = lbound(batch, n, g);
  int hi = lbound(batch, n, g + 1);
  float s = 0.0f;
  if (hi > lo){
    int per = (hi - lo + nch - 1) / nch;
    int b = lo + chunk * per;
    int e = min(b + per, hi);
    for (int r = b; r < e; ++r) s += node_out[(size_t)r * D + d];
  }
  atomicAdd(&sums[g * D + d], s);
  __threadfence();
  __syncthreads();
  __shared__ int tk;
  if (d == 0) tk = atomicAdd(&gdone[g], 1);
  __syncthreads();
  if (tk == nch - 1){
    float c = (float)((hi - lo) > 1 ? (hi - lo) : 1);
    float v = atomicAdd(&sums[g * D + d], 0.0f);  // device-coherent read
    out[g * D + d] = v / c;
  }
}

extern "C" void kernel_launch(void* const* d_in, const int* in_sizes, int n_in,
                              void* d_out, int out_size, void* d_ws, size_t ws_size,
                              hipStream_t stream){
  const float* x     = (const float*)d_in[0];
  const int*   eidx  = (const int*)d_in[1];
  const float* eattr = (const float*)d_in[2];
  const int*   batch = (const int*)d_in[3];
  const float* w1 = (const float*)d_in[4];
  const float* b1 = (const float*)d_in[5];
  const float* w2 = (const float*)d_in[6];
  const float* b2 = (const float*)d_in[7];
  const float* w3 = (const float*)d_in[8];
  const float* b3 = (const float*)d_in[9];
  const float* w4 = (const float*)d_in[10];
  const float* b4 = (const float*)d_in[11];
  const float* w5 = (const float*)d_in[12];
  const float* b5 = (const float*)d_in[13];
  float* out = (float*)d_out;

  const int N = in_sizes[0] / D;
  const int E = in_sizes[2];
  const int* srcI = eidx;
  const int* dstI = eidx + E;
  const int NB = (N + 255) / 256;
  const int NT = (N + 15) / 16;
  const int NG = out_size / D;

  char* base = (char*)d_ws;
  size_t off = 0;
  auto alloc = [&](size_t bytes) -> char* {
    char* p = base + off;
    off = (off + bytes + 255) & ~(size_t)255;
    return p;
  };
  char* zbase = base;
  int*   deg   = (int*)alloc((size_t)N * 4);
  int*   fill  = (int*)alloc((size_t)N * 4);
  float* sums  = (float*)alloc((size_t)out_size * 4);
  int*   gdone = (int*)alloc((size_t)NG * 4);
  size_t zbytes = off;
  float* node_acc = (float*)alloc((size_t)N * D * 4);
  unsigned short* x2v = (unsigned short*)alloc((size_t)N * D * 2);
  float* x3v      = (float*)alloc((size_t)N * D * 4);
  unsigned short* x4v = (unsigned short*)alloc((size_t)N * D * 2);
  float* p5       = (float*)alloc((size_t)N * 4);
  float* pb       = (float*)alloc((size_t)N * 4);
  int*   rowp     = (int*)alloc((size_t)(N + 1) * 4);
  int*   partials = (int*)alloc((size_t)(NB + 1) * 4);
  int2*  sortedSE = (int2*)alloc((size_t)E * 8);
  unsigned short* wt_h = (unsigned short*)alloc((size_t)4 * D * D * 2);
  unsigned short* wt_l = (unsigned short*)alloc((size_t)4 * D * D * 2);
  (void)ws_size; (void)n_in;

  hipMemsetAsync(zbase, 0, zbytes, stream);

  BuildArgs A;
  A.x = x;
  A.w1 = w1; A.b1 = b1; A.w2 = w2; A.b2 = b2;
  A.w3 = w3; A.b3 = b3; A.w4 = w4; A.b4 = b4;
  A.w5 = w5; A.b5 = b5;
  A.srcI = srcI; A.dstI = dstI; A.eattr = eattr;
  A.wt_h = wt_h; A.wt_l = wt_l;
  A.acc_o = node_acc; A.x2o = x2v; A.x3o = x3v; A.x4o = x4v;
  A.p5 = p5; A.pb = pb;
  A.deg = deg; A.fill = fill; A.rowp = rowp; A.partials = partials;
  A.sortedSE = sortedSE;
  A.N = N; A.E = E; A.NB = NB; A.NT = NT;

  void* kargs[] = { &A };
  hipError_t cerr = hipLaunchCooperativeKernel((const void*)k_build, dim3(512),
                                               dim3(256), kargs, 0, stream);
  if (cerr != hipSuccess){
    // deterministic fallback: same phases as separate stream-ordered launches
    k_wprep_deg<<<dim3((E + 255) / 256), dim3(256), 0, stream>>>(A);
    k_transform_sep<<<dim3(NT), dim3(256), 0, stream>>>(A);
    k_scanA_sep<<<dim3(NB), dim3(256), 0, stream>>>(A);
    k_scanB_sep<<<dim3(1), dim3(256), 0, stream>>>(A);
    k_scatter_sep<<<dim3((E + 255) / 256), dim3(256), 0, stream>>>(A);
  }

  k_attn<<<dim3((N + 3) / 4), dim3(256), 0, stream>>>(
      x2v, x3v, x4v, p5, pb, sortedSE, rowp, partials, node_acc, N);
  k_pool<<<dim3(NG, 32), dim3(D), 0, stream>>>(
      node_acc, batch, sums, gdone, out, N);
}

// Round 8
// 357.675 us; speedup vs baseline: 1.5894x; 1.5894x over previous
//
#include <hip/hip_runtime.h>
#include <math.h>

#define D 96
#define RSQ 0.10206207261596577f  // 1/sqrt(96)
#define TSTRIDE 104               // padded LDS row stride (bf16 elems)

typedef __attribute__((ext_vector_type(8))) short short8;
typedef __attribute__((ext_vector_type(4))) float f32x4;

__device__ __forceinline__ unsigned short f2bf(float f){
  unsigned u = __float_as_uint(f);
  unsigned r = (u + 0x7fff + ((u >> 16) & 1)) >> 16;  // RNE
  return (unsigned short)r;
}
__device__ __forceinline__ float bf2f(unsigned short h){
  return __uint_as_float(((unsigned)h) << 16);
}
__device__ __forceinline__ float bflo(unsigned u){ return __uint_as_float(u << 16); }
__device__ __forceinline__ float bfhi(unsigned u){ return __uint_as_float(u & 0xffff0000u); }
__device__ __forceinline__ int lbound(const int* __restrict__ a, int n, int v){
  int lo = 0, hi = n;
  while (lo < hi){ int mid = (lo + hi) >> 1; if (a[mid] < v) lo = mid + 1; else hi = mid; }
  return lo;
}

// K0: weight prep (transpose + hi/lo bf16 split) fused with degree histogram
__global__ __launch_bounds__(256) void k_wprep_deg(
    const float* __restrict__ w1, const float* __restrict__ w2,
    const float* __restrict__ w3, const float* __restrict__ w4,
    unsigned short* __restrict__ wt_h, unsigned short* __restrict__ wt_l,
    const int* __restrict__ dstI, int* __restrict__ deg, int E){
  int gtid = blockIdx.x * 256 + threadIdx.x;
  if (gtid < 4 * D * D){
    int m = gtid / (D * D);
    int r = gtid % (D * D);
    int nn = r / D, k = r % D;
    const float* w = (m == 0) ? w1 : (m == 1) ? w2 : (m == 2) ? w3 : w4;
    float v = w[k * D + nn];
    unsigned short h = f2bf(v);
    wt_h[gtid] = h;
    wt_l[gtid] = f2bf(v - bf2f(h));
  }
  if (gtid < E) atomicAdd(&deg[dstI[gtid]], 1);
}

// K1: node transforms via split-bf16 MFMA. Block = 16 nodes, 4 waves; wave w computes x@w_w (16x96).
// x2/x4 written as bf16; acc/x3 stay f32. Wave 2 also computes fused p5/pb.
__global__ __launch_bounds__(256) void k_transform_mfma(
    const float* __restrict__ x,
    const unsigned short* __restrict__ wt_h, const unsigned short* __restrict__ wt_l,
    const float* __restrict__ b1, const float* __restrict__ b2,
    const float* __restrict__ b3, const float* __restrict__ b4,
    const float* __restrict__ w5, const float* __restrict__ b5,
    float* __restrict__ acc_o, unsigned short* __restrict__ x2o,
    float* __restrict__ x3o, unsigned short* __restrict__ x4o,
    float* __restrict__ p5, float* __restrict__ pb, int n){
  __shared__ __align__(16) unsigned short xs_h[16][TSTRIDE];
  __shared__ __align__(16) unsigned short xs_l[16][TSTRIDE];
  int tid = threadIdx.x;
  int n0 = blockIdx.x * 16;
  for (int e = tid; e < 16 * D; e += 256){
    int r = e / D, c = e % D;
    int node = n0 + r;
    float v = (node < n) ? x[(size_t)node * D + c] : 0.0f;
    unsigned short h = f2bf(v);
    xs_h[r][c] = h;
    xs_l[r][c] = f2bf(v - bf2f(h));
  }
  __syncthreads();

  int wv = tid >> 6;
  int lane = tid & 63;
  int lr = lane & 15;
  int kg = lane >> 4;

  f32x4 acc0 = {0,0,0,0}, acc1 = {0,0,0,0}, acc2 = {0,0,0,0};
  f32x4 acc3 = {0,0,0,0}, acc4 = {0,0,0,0}, acc5 = {0,0,0,0};
  const unsigned short* wtm_h = wt_h + (size_t)wv * D * D;
  const unsigned short* wtm_l = wt_l + (size_t)wv * D * D;

  #pragma unroll
  for (int k0 = 0; k0 < D; k0 += 32){
    int kb = k0 + kg * 8;
    short8 ah = *(const short8*)&xs_h[lr][kb];
    short8 al = *(const short8*)&xs_l[lr][kb];
    #pragma unroll
    for (int nc = 0; nc < 6; ++nc){
      int col = nc * 16 + lr;
      short8 bh = *(const short8*)(wtm_h + col * D + kb);
      short8 bl = *(const short8*)(wtm_l + col * D + kb);
      f32x4 a = (nc == 0) ? acc0 : (nc == 1) ? acc1 : (nc == 2) ? acc2
              : (nc == 3) ? acc3 : (nc == 4) ? acc4 : acc5;
      a = __builtin_amdgcn_mfma_f32_16x16x32_bf16(ah, bh, a, 0, 0, 0);
      a = __builtin_amdgcn_mfma_f32_16x16x32_bf16(ah, bl, a, 0, 0, 0);
      a = __builtin_amdgcn_mfma_f32_16x16x32_bf16(al, bh, a, 0, 0, 0);
      if (nc == 0) acc0 = a; else if (nc == 1) acc1 = a; else if (nc == 2) acc2 = a;
      else if (nc == 3) acc3 = a; else if (nc == 4) acc4 = a; else acc5 = a;
    }
  }

  const float* bias = (wv == 0) ? b1 : (wv == 1) ? b2 : (wv == 2) ? b3 : b4;
  float p5p0 = 0, p5p1 = 0, p5p2 = 0, p5p3 = 0;
  float pbp0 = 0, pbp1 = 0, pbp2 = 0, pbp3 = 0;
  #pragma unroll
  for (int nc = 0; nc < 6; ++nc){
    int col = nc * 16 + lr;
    float bb = bias[col];
    float w5v = w5[col], b5v = b5[col];
    f32x4 a = (nc == 0) ? acc0 : (nc == 1) ? acc1 : (nc == 2) ? acc2
            : (nc == 3) ? acc3 : (nc == 4) ? acc4 : acc5;
    #pragma unroll
    for (int q = 0; q < 4; ++q){
      float v = a[q] + bb;
      int row = kg * 4 + q;
      if (n0 + row < n){
        size_t o = (size_t)(n0 + row) * D + col;
        if (wv == 0) acc_o[o] = v;
        else if (wv == 1) x2o[o] = f2bf(v);
        else if (wv == 2) x3o[o] = v;
        else x4o[o] = f2bf(v);
      }
      float t5 = v * w5v, tb = v * b5v;
      if (q == 0){ p5p0 += t5; pbp0 += tb; }
      else if (q == 1){ p5p1 += t5; pbp1 += tb; }
      else if (q == 2){ p5p2 += t5; pbp2 += tb; }
      else { p5p3 += t5; pbp3 += tb; }
    }
  }
  if (wv == 2){
    #pragma unroll
    for (int off = 1; off < 16; off <<= 1){
      p5p0 += __shfl_xor(p5p0, off); pbp0 += __shfl_xor(pbp0, off);
      p5p1 += __shfl_xor(p5p1, off); pbp1 += __shfl_xor(pbp1, off);
      p5p2 += __shfl_xor(p5p2, off); pbp2 += __shfl_xor(pbp2, off);
      p5p3 += __shfl_xor(p5p3, off); pbp3 += __shfl_xor(pbp3, off);
    }
    if (lr == 0){
      int row = kg * 4;
      if (n0 + row < n)     { p5[n0 + row]     = p5p0; pb[n0 + row]     = pbp0; }
      if (n0 + row + 1 < n) { p5[n0 + row + 1] = p5p1; pb[n0 + row + 1] = pbp1; }
      if (n0 + row + 2 < n) { p5[n0 + row + 2] = p5p2; pb[n0 + row + 2] = pbp2; }
      if (n0 + row + 3 < n) { p5[n0 + row + 3] = p5p3; pb[n0 + row + 3] = pbp3; }
    }
  }
}

// K3a: per-block exclusive scan (256 elements/block) + block totals
__global__ __launch_bounds__(256) void k_scanA(
    const int* __restrict__ deg, int* __restrict__ rowp,
    int* __restrict__ partials, int n){
  __shared__ int ws[4];
  int tid = threadIdx.x, lane = tid & 63, wid = tid >> 6;
  int i = blockIdx.x * 256 + tid;
  int v = (i < n) ? deg[i] : 0;
  int s = v;
  #pragma unroll
  for (int off = 1; off < 64; off <<= 1){ int u = __shfl_up(s, off); if (lane >= off) s += u; }
  if (lane == 63) ws[wid] = s;
  __syncthreads();
  if (tid < 4){
    int u = ws[tid];
    #pragma unroll
    for (int off = 1; off < 4; off <<= 1){ int q = __shfl_up(u, off); if (tid >= off) u += q; }
    ws[tid] = u;
  }
  __syncthreads();
  int woff = wid ? ws[wid - 1] : 0;
  if (i < n) rowp[i] = woff + s - v;   // block-local exclusive prefix
  if (tid == 255) partials[blockIdx.x] = ws[3];
}

// K3b: exclusive scan of block totals (in place) + grand total -> rowp[n]
__global__ __launch_bounds__(256) void k_scanB(
    int* __restrict__ partials, int* __restrict__ rowp, int nb, int n){
  __shared__ int ws[4];
  int tid = threadIdx.x, lane = tid & 63, wid = tid >> 6;
  int running = 0;
  for (int base = 0; base < nb; base += 256){
    int i = base + tid;
    int v = (i < nb) ? partials[i] : 0;
    int s = v;
    #pragma unroll
    for (int off = 1; off < 64; off <<= 1){ int u = __shfl_up(s, off); if (lane >= off) s += u; }
    if (lane == 63) ws[wid] = s;
    __syncthreads();
    if (tid < 4){
      int u = ws[tid];
      #pragma unroll
      for (int off = 1; off < 4; off <<= 1){ int q = __shfl_up(u, off); if (tid >= off) u += q; }
      ws[tid] = u;
    }
    __syncthreads();
    int woff = wid ? ws[wid - 1] : 0;
    if (i < nb) partials[i] = running + woff + s - v;
    running += ws[3];
    __syncthreads();
  }
  if (tid == 0) rowp[n] = running;
}

// K4: scatter (src, eattr) into CSR order keyed by dst (block offset folded in)
__global__ __launch_bounds__(256) void k_scatter(
    const int* __restrict__ srcI, const int* __restrict__ dstI,
    const float* __restrict__ eattr, const int* __restrict__ rowp,
    const int* __restrict__ partials, int* __restrict__ fill,
    int2* __restrict__ sortedSE, int E){
  int e = blockIdx.x * blockDim.x + threadIdx.x;
  if (e >= E) return;
  int t = dstI[e];
  int pos = rowp[t] + partials[t >> 8] + atomicAdd(&fill[t], 1);
  sortedSE[pos] = make_int2(srcI[e], __float_as_int(eattr[e]));
}

// K5: fused attention per dst row — one wave per node, 16 lanes per edge,
// 4 edges in flight; bf16 gathers (3 uint per row per lane); online softmax.
__global__ __launch_bounds__(256) void k_attn(
    const unsigned short* __restrict__ x2b, const float* __restrict__ x3,
    const unsigned short* __restrict__ x4b, const float* __restrict__ p5,
    const float* __restrict__ pb, const int2* __restrict__ sortedSE,
    const int* __restrict__ rowp, const int* __restrict__ partials,
    float* __restrict__ node_acc, int n){
  int t = blockIdx.x * 4 + (threadIdx.x >> 6);
  int lane = threadIdx.x & 63;
  if (t >= n) return;
  int beg = rowp[t] + partials[t >> 8];
  int end = (t + 1 < n) ? (rowp[t + 1] + partials[(t + 1) >> 8]) : rowp[n];
  if (beg == end) return;
  int j = lane & 15;

  const float2* r3 = (const float2*)(x3 + (size_t)t * D);
  float2 v0 = r3[j], v1 = r3[j + 16], v2 = r3[j + 32];
  float p5t = p5[t], pbt = pb[t];

  float m = -INFINITY, dsum = 0.0f;
  float a0 = 0, a1 = 0, a2 = 0, a3 = 0, a4 = 0, a5 = 0;

  for (int c = beg; c < end; c += 4){
    int g = lane >> 4;
    int ei = c + g;
    bool act = ei < end;
    int2 se = sortedSE[act ? ei : end - 1];
    const unsigned* r4 = (const unsigned*)(x4b + (size_t)se.x * D);
    unsigned u0 = r4[j], u1 = r4[j + 16], u2 = r4[j + 32];
    float s = v0.x * bflo(u0) + v0.y * bfhi(u0)
            + v1.x * bflo(u1) + v1.y * bfhi(u1)
            + v2.x * bflo(u2) + v2.y * bfhi(u2);
    s += __shfl_xor(s, 1); s += __shfl_xor(s, 2);
    s += __shfl_xor(s, 4); s += __shfl_xor(s, 8);
    float sc = act ? (s + __int_as_float(se.y) * p5t + pbt) * RSQ : -INFINITY;
    float mc = fmaxf(sc, __shfl_xor(sc, 16));
    mc = fmaxf(mc, __shfl_xor(mc, 32));
    if (mc > m){
      float r = __expf(m - mc);
      dsum *= r; a0 *= r; a1 *= r; a2 *= r; a3 *= r; a4 *= r; a5 *= r;
      m = mc;
    }
    float w = __expf(sc - m);
    dsum += w;
    const unsigned* r2 = (const unsigned*)(x2b + (size_t)se.x * D);
    unsigned q0 = r2[j], q1 = r2[j + 16], q2 = r2[j + 32];
    a0 += w * bflo(q0); a1 += w * bfhi(q0);
    a2 += w * bflo(q1); a3 += w * bfhi(q1);
    a4 += w * bflo(q2); a5 += w * bfhi(q2);
  }
  a0 += __shfl_xor(a0, 16); a0 += __shfl_xor(a0, 32);
  a1 += __shfl_xor(a1, 16); a1 += __shfl_xor(a1, 32);
  a2 += __shfl_xor(a2, 16); a2 += __shfl_xor(a2, 32);
  a3 += __shfl_xor(a3, 16); a3 += __shfl_xor(a3, 32);
  a4 += __shfl_xor(a4, 16); a4 += __shfl_xor(a4, 32);
  a5 += __shfl_xor(a5, 16); a5 += __shfl_xor(a5, 32);
  dsum += __shfl_xor(dsum, 16); dsum += __shfl_xor(dsum, 32);
  float inv = 1.0f / (dsum + 1e-16f);
  if (lane < 16){
    size_t o = (size_t)t * D + 2 * j;   // elems 2j,2j+1 / +32 / +64
    node_acc[o]      += a0 * inv;
    node_acc[o + 1]  += a1 * inv;
    node_acc[o + 32] += a2 * inv;
    node_acc[o + 33] += a3 * inv;
    node_acc[o + 64] += a4 * inv;
    node_acc[o + 65] += a5 * inv;
  }
}

// K6: per-graph partial sums + fused finalization (last-chunk ticket; proven R7)
__global__ __launch_bounds__(96) void k_pool(
    const float* __restrict__ node_out, const int* __restrict__ batch,
    float* __restrict__ sums, int* __restrict__ gdone,
    float* __restrict__ out, int n){
  int g = blockIdx.x;
  int chunk = blockIdx.y, nch = gridDim.y;
  int d = threadIdx.x;
  int lo = lbound(batch, n, g);
  int hi = lbound(batch, n, g + 1);
  float s = 0.0f;
  if (hi > lo){
    int per = (hi - lo + nch - 1) / nch;
    int b = lo + chunk * per;
    int e = min(b + per, hi);
    for (int r = b; r < e; ++r) s += node_out[(size_t)r * D + d];
  }
  atomicAdd(&sums[g * D + d], s);
  __threadfence();
  __syncthreads();
  __shared__ int tk;
  if (d == 0) tk = atomicAdd(&gdone[g], 1);
  __syncthreads();
  if (tk == nch - 1){
    float c = (float)((hi - lo) > 1 ? (hi - lo) : 1);
    float v = atomicAdd(&sums[g * D + d], 0.0f);  // device-coherent read
    out[g * D + d] = v / c;
  }
}

extern "C" void kernel_launch(void* const* d_in, const int* in_sizes, int n_in,
                              void* d_out, int out_size, void* d_ws, size_t ws_size,
                              hipStream_t stream){
  const float* x     = (const float*)d_in[0];
  const int*   eidx  = (const int*)d_in[1];
  const float* eattr = (const float*)d_in[2];
  const int*   batch = (const int*)d_in[3];
  const float* w1 = (const float*)d_in[4];
  const float* b1 = (const float*)d_in[5];
  const float* w2 = (const float*)d_in[6];
  const float* b2 = (const float*)d_in[7];
  const float* w3 = (const float*)d_in[8];
  const float* b3 = (const float*)d_in[9];
  const float* w4 = (const float*)d_in[10];
  const float* b4 = (const float*)d_in[11];
  const float* w5 = (const float*)d_in[12];
  const float* b5 = (const float*)d_in[13];
  float* out = (float*)d_out;

  const int N = in_sizes[0] / D;
  const int E = in_sizes[2];
  const int* srcI = eidx;
  const int* dstI = eidx + E;
  const int NB = (N + 255) / 256;
  const int NG = out_size / D;

  char* base = (char*)d_ws;
  size_t off = 0;
  auto alloc = [&](size_t bytes) -> char* {
    char* p = base + off;
    off = (off + bytes + 255) & ~(size_t)255;
    return p;
  };
  char* zbase = base;
  int*   deg   = (int*)alloc((size_t)N * 4);
  int*   fill  = (int*)alloc((size_t)N * 4);
  float* sums  = (float*)alloc((size_t)out_size * 4);
  int*   gdone = (int*)alloc((size_t)NG * 4);
  size_t zbytes = off;
  float* node_acc = (float*)alloc((size_t)N * D * 4);
  unsigned short* x2v = (unsigned short*)alloc((size_t)N * D * 2);
  float* x3v      = (float*)alloc((size_t)N * D * 4);
  unsigned short* x4v = (unsigned short*)alloc((size_t)N * D * 2);
  float* p5       = (float*)alloc((size_t)N * 4);
  float* pb       = (float*)alloc((size_t)N * 4);
  int*   rowp     = (int*)alloc((size_t)(N + 1) * 4);
  int*   partials = (int*)alloc((size_t)(NB + 1) * 4);
  int2*  sortedSE = (int2*)alloc((size_t)E * 8);
  unsigned short* wt_h = (unsigned short*)alloc((size_t)4 * D * D * 2);
  unsigned short* wt_l = (unsigned short*)alloc((size_t)4 * D * D * 2);
  (void)ws_size; (void)n_in;

  hipMemsetAsync(zbase, 0, zbytes, stream);

  k_wprep_deg<<<dim3((E + 255) / 256), dim3(256), 0, stream>>>(
      w1, w2, w3, w4, wt_h, wt_l, dstI, deg, E);
  k_transform_mfma<<<dim3((N + 15) / 16), dim3(256), 0, stream>>>(
      x, wt_h, wt_l, b1, b2, b3, b4, w5, b5,
      node_acc, x2v, x3v, x4v, p5, pb, N);
  k_scanA<<<dim3(NB), dim3(256), 0, stream>>>(deg, rowp, partials, N);
  k_scanB<<<dim3(1), dim3(256), 0, stream>>>(partials, rowp, NB, N);
  k_scatter<<<dim3((E + 255) / 256), dim3(256), 0, stream>>>(
      srcI, dstI, eattr, rowp, partials, fill, sortedSE, E);
  k_attn<<<dim3((N + 3) / 4), dim3(256), 0, stream>>>(
      x2v, x3v, x4v, p5, pb, sortedSE, rowp, partials, node_acc, N);
  k_pool<<<dim3(NG, 32), dim3(D), 0, stream>>>(
      node_acc, batch, sums, gdone, out, N);
}

// Round 9
// 302.256 us; speedup vs baseline: 1.8809x; 1.1833x over previous
//
#include <hip/hip_runtime.h>
#include <math.h>

#define D 96
#define RSQ 0.10206207261596577f  // 1/sqrt(96)
#define TSTRIDE 104               // padded LDS row stride (bf16 elems)

typedef __attribute__((ext_vector_type(8))) short short8;
typedef __attribute__((ext_vector_type(4))) float f32x4;

__device__ __forceinline__ unsigned short f2bf(float f){
  unsigned u = __float_as_uint(f);
  unsigned r = (u + 0x7fff + ((u >> 16) & 1)) >> 16;  // RNE
  return (unsigned short)r;
}
__device__ __forceinline__ float bf2f(unsigned short h){
  return __uint_as_float(((unsigned)h) << 16);
}
__device__ __forceinline__ float bflo(unsigned u){ return __uint_as_float(u << 16); }
__device__ __forceinline__ float bfhi(unsigned u){ return __uint_as_float(u & 0xffff0000u); }
__device__ __forceinline__ int lbound(const int* __restrict__ a, int n, int v){
  int lo = 0, hi = n;
  while (lo < hi){ int mid = (lo + hi) >> 1; if (a[mid] < v) lo = mid + 1; else hi = mid; }
  return lo;
}

// K0: weight prep (transpose + hi/lo bf16 split) fused with degree histogram
__global__ __launch_bounds__(256) void k_wprep_deg(
    const float* __restrict__ w1, const float* __restrict__ w2,
    const float* __restrict__ w3, const float* __restrict__ w4,
    unsigned short* __restrict__ wt_h, unsigned short* __restrict__ wt_l,
    const int* __restrict__ dstI, int* __restrict__ deg, int E){
  int gtid = blockIdx.x * 256 + threadIdx.x;
  if (gtid < 4 * D * D){
    int m = gtid / (D * D);
    int r = gtid % (D * D);
    int nn = r / D, k = r % D;
    const float* w = (m == 0) ? w1 : (m == 1) ? w2 : (m == 2) ? w3 : w4;
    float v = w[k * D + nn];
    unsigned short h = f2bf(v);
    wt_h[gtid] = h;
    wt_l[gtid] = f2bf(v - bf2f(h));
  }
  if (gtid < E) atomicAdd(&deg[dstI[gtid]], 1);
}

// K1: node transforms via split-bf16 MFMA. Block = 16 nodes, 4 waves; wave w computes x@w_w (16x96).
// x2/x4 written as bf16; acc/x3 stay f32. Wave 2 also computes fused p5/pb.
__global__ __launch_bounds__(256) void k_transform_mfma(
    const float* __restrict__ x,
    const unsigned short* __restrict__ wt_h, const unsigned short* __restrict__ wt_l,
    const float* __restrict__ b1, const float* __restrict__ b2,
    const float* __restrict__ b3, const float* __restrict__ b4,
    const float* __restrict__ w5, const float* __restrict__ b5,
    float* __restrict__ acc_o, unsigned short* __restrict__ x2o,
    float* __restrict__ x3o, unsigned short* __restrict__ x4o,
    float* __restrict__ p5, float* __restrict__ pb, int n){
  __shared__ __align__(16) unsigned short xs_h[16][TSTRIDE];
  __shared__ __align__(16) unsigned short xs_l[16][TSTRIDE];
  int tid = threadIdx.x;
  int n0 = blockIdx.x * 16;
  for (int e = tid; e < 16 * D; e += 256){
    int r = e / D, c = e % D;
    int node = n0 + r;
    float v = (node < n) ? x[(size_t)node * D + c] : 0.0f;
    unsigned short h = f2bf(v);
    xs_h[r][c] = h;
    xs_l[r][c] = f2bf(v - bf2f(h));
  }
  __syncthreads();

  int wv = tid >> 6;
  int lane = tid & 63;
  int lr = lane & 15;
  int kg = lane >> 4;

  f32x4 acc0 = {0,0,0,0}, acc1 = {0,0,0,0}, acc2 = {0,0,0,0};
  f32x4 acc3 = {0,0,0,0}, acc4 = {0,0,0,0}, acc5 = {0,0,0,0};
  const unsigned short* wtm_h = wt_h + (size_t)wv * D * D;
  const unsigned short* wtm_l = wt_l + (size_t)wv * D * D;

  #pragma unroll
  for (int k0 = 0; k0 < D; k0 += 32){
    int kb = k0 + kg * 8;
    short8 ah = *(const short8*)&xs_h[lr][kb];
    short8 al = *(const short8*)&xs_l[lr][kb];
    #pragma unroll
    for (int nc = 0; nc < 6; ++nc){
      int col = nc * 16 + lr;
      short8 bh = *(const short8*)(wtm_h + col * D + kb);
      short8 bl = *(const short8*)(wtm_l + col * D + kb);
      f32x4 a = (nc == 0) ? acc0 : (nc == 1) ? acc1 : (nc == 2) ? acc2
              : (nc == 3) ? acc3 : (nc == 4) ? acc4 : acc5;
      a = __builtin_amdgcn_mfma_f32_16x16x32_bf16(ah, bh, a, 0, 0, 0);
      a = __builtin_amdgcn_mfma_f32_16x16x32_bf16(ah, bl, a, 0, 0, 0);
      a = __builtin_amdgcn_mfma_f32_16x16x32_bf16(al, bh, a, 0, 0, 0);
      if (nc == 0) acc0 = a; else if (nc == 1) acc1 = a; else if (nc == 2) acc2 = a;
      else if (nc == 3) acc3 = a; else if (nc == 4) acc4 = a; else acc5 = a;
    }
  }

  const float* bias = (wv == 0) ? b1 : (wv == 1) ? b2 : (wv == 2) ? b3 : b4;
  float p5p0 = 0, p5p1 = 0, p5p2 = 0, p5p3 = 0;
  float pbp0 = 0, pbp1 = 0, pbp2 = 0, pbp3 = 0;
  #pragma unroll
  for (int nc = 0; nc < 6; ++nc){
    int col = nc * 16 + lr;
    float bb = bias[col];
    float w5v = w5[col], b5v = b5[col];
    f32x4 a = (nc == 0) ? acc0 : (nc == 1) ? acc1 : (nc == 2) ? acc2
            : (nc == 3) ? acc3 : (nc == 4) ? acc4 : acc5;
    #pragma unroll
    for (int q = 0; q < 4; ++q){
      float v = a[q] + bb;
      int row = kg * 4 + q;
      if (n0 + row < n){
        size_t o = (size_t)(n0 + row) * D + col;
        if (wv == 0) acc_o[o] = v;
        else if (wv == 1) x2o[o] = f2bf(v);
        else if (wv == 2) x3o[o] = v;
        else x4o[o] = f2bf(v);
      }
      float t5 = v * w5v, tb = v * b5v;
      if (q == 0){ p5p0 += t5; pbp0 += tb; }
      else if (q == 1){ p5p1 += t5; pbp1 += tb; }
      else if (q == 2){ p5p2 += t5; pbp2 += tb; }
      else { p5p3 += t5; pbp3 += tb; }
    }
  }
  if (wv == 2){
    #pragma unroll
    for (int off = 1; off < 16; off <<= 1){
      p5p0 += __shfl_xor(p5p0, off); pbp0 += __shfl_xor(pbp0, off);
      p5p1 += __shfl_xor(p5p1, off); pbp1 += __shfl_xor(pbp1, off);
      p5p2 += __shfl_xor(p5p2, off); pbp2 += __shfl_xor(pbp2, off);
      p5p3 += __shfl_xor(p5p3, off); pbp3 += __shfl_xor(pbp3, off);
    }
    if (lr == 0){
      int row = kg * 4;
      if (n0 + row < n)     { p5[n0 + row]     = p5p0; pb[n0 + row]     = pbp0; }
      if (n0 + row + 1 < n) { p5[n0 + row + 1] = p5p1; pb[n0 + row + 1] = pbp1; }
      if (n0 + row + 2 < n) { p5[n0 + row + 2] = p5p2; pb[n0 + row + 2] = pbp2; }
      if (n0 + row + 3 < n) { p5[n0 + row + 3] = p5p3; pb[n0 + row + 3] = pbp3; }
    }
  }
}

// K3a: per-block exclusive scan (256 elements/block) + block totals
__global__ __launch_bounds__(256) void k_scanA(
    const int* __restrict__ deg, int* __restrict__ rowp,
    int* __restrict__ partials, int n){
  __shared__ int ws[4];
  int tid = threadIdx.x, lane = tid & 63, wid = tid >> 6;
  int i = blockIdx.x * 256 + tid;
  int v = (i < n) ? deg[i] : 0;
  int s = v;
  #pragma unroll
  for (int off = 1; off < 64; off <<= 1){ int u = __shfl_up(s, off); if (lane >= off) s += u; }
  if (lane == 63) ws[wid] = s;
  __syncthreads();
  if (tid < 4){
    int u = ws[tid];
    #pragma unroll
    for (int off = 1; off < 4; off <<= 1){ int q = __shfl_up(u, off); if (tid >= off) u += q; }
    ws[tid] = u;
  }
  __syncthreads();
  int woff = wid ? ws[wid - 1] : 0;
  if (i < n) rowp[i] = woff + s - v;   // block-local exclusive prefix
  if (tid == 255) partials[blockIdx.x] = ws[3];
}

// K3b: exclusive scan of block totals (in place) + grand total -> rowp[n]
__global__ __launch_bounds__(256) void k_scanB(
    int* __restrict__ partials, int* __restrict__ rowp, int nb, int n){
  __shared__ int ws[4];
  int tid = threadIdx.x, lane = tid & 63, wid = tid >> 6;
  int running = 0;
  for (int base = 0; base < nb; base += 256){
    int i = base + tid;
    int v = (i < nb) ? partials[i] : 0;
    int s = v;
    #pragma unroll
    for (int off = 1; off < 64; off <<= 1){ int u = __shfl_up(s, off); if (lane >= off) s += u; }
    if (lane == 63) ws[wid] = s;
    __syncthreads();
    if (tid < 4){
      int u = ws[tid];
      #pragma unroll
      for (int off = 1; off < 4; off <<= 1){ int q = __shfl_up(u, off); if (tid >= off) u += q; }
      ws[tid] = u;
    }
    __syncthreads();
    int woff = wid ? ws[wid - 1] : 0;
    if (i < nb) partials[i] = running + woff + s - v;
    running += ws[3];
    __syncthreads();
  }
  if (tid == 0) rowp[n] = running;
}

// K4: scatter (src, eattr) into CSR order keyed by dst (block offset folded in)
__global__ __launch_bounds__(256) void k_scatter(
    const int* __restrict__ srcI, const int* __restrict__ dstI,
    const float* __restrict__ eattr, const int* __restrict__ rowp,
    const int* __restrict__ partials, int* __restrict__ fill,
    int2* __restrict__ sortedSE, int E){
  int e = blockIdx.x * blockDim.x + threadIdx.x;
  if (e >= E) return;
  int t = dstI[e];
  int pos = rowp[t] + partials[t >> 8] + atomicAdd(&fill[t], 1);
  sortedSE[pos] = make_int2(srcI[e], __float_as_int(eattr[e]));
}

// K5: fused attention per dst row — one wave per node, 16 lanes per edge,
// 8 edges in flight (2×4 unroll, proven R7); bf16 gathers; online softmax.
__global__ __launch_bounds__(256) void k_attn(
    const unsigned short* __restrict__ x2b, const float* __restrict__ x3,
    const unsigned short* __restrict__ x4b, const float* __restrict__ p5,
    const float* __restrict__ pb, const int2* __restrict__ sortedSE,
    const int* __restrict__ rowp, const int* __restrict__ partials,
    float* __restrict__ node_acc, int n){
  int t = blockIdx.x * 4 + (threadIdx.x >> 6);
  int lane = threadIdx.x & 63;
  if (t >= n) return;
  int beg = rowp[t] + partials[t >> 8];
  int end = (t + 1 < n) ? (rowp[t + 1] + partials[(t + 1) >> 8]) : rowp[n];
  if (beg == end) return;
  int j = lane & 15;
  int g = lane >> 4;

  const float2* r3 = (const float2*)(x3 + (size_t)t * D);
  float2 v0 = r3[j], v1 = r3[j + 16], v2 = r3[j + 32];
  float p5t = p5[t], pbt = pb[t];

  float m = -INFINITY, dsum = 0.0f;
  float a0 = 0, a1 = 0, a2 = 0, a3 = 0, a4 = 0, a5 = 0;

  for (int c = beg; c < end; c += 8){
    int eA = c + g, eB = c + 4 + g;
    bool actA = eA < end, actB = eB < end;
    int2 seA = sortedSE[actA ? eA : end - 1];
    int2 seB = sortedSE[actB ? eB : end - 1];
    const unsigned* r4A = (const unsigned*)(x4b + (size_t)seA.x * D);
    const unsigned* r4B = (const unsigned*)(x4b + (size_t)seB.x * D);
    unsigned uA0 = r4A[j], uA1 = r4A[j + 16], uA2 = r4A[j + 32];
    unsigned uB0 = r4B[j], uB1 = r4B[j + 16], uB2 = r4B[j + 32];
    float sA = v0.x * bflo(uA0) + v0.y * bfhi(uA0)
             + v1.x * bflo(uA1) + v1.y * bfhi(uA1)
             + v2.x * bflo(uA2) + v2.y * bfhi(uA2);
    float sB = v0.x * bflo(uB0) + v0.y * bfhi(uB0)
             + v1.x * bflo(uB1) + v1.y * bfhi(uB1)
             + v2.x * bflo(uB2) + v2.y * bfhi(uB2);
    sA += __shfl_xor(sA, 1); sA += __shfl_xor(sA, 2);
    sA += __shfl_xor(sA, 4); sA += __shfl_xor(sA, 8);
    sB += __shfl_xor(sB, 1); sB += __shfl_xor(sB, 2);
    sB += __shfl_xor(sB, 4); sB += __shfl_xor(sB, 8);
    float scA = actA ? (sA + __int_as_float(seA.y) * p5t + pbt) * RSQ : -INFINITY;
    float scB = actB ? (sB + __int_as_float(seB.y) * p5t + pbt) * RSQ : -INFINITY;
    float mc = fmaxf(scA, scB);
    mc = fmaxf(mc, __shfl_xor(mc, 16));
    mc = fmaxf(mc, __shfl_xor(mc, 32));
    if (mc > m){
      float r = __expf(m - mc);   // 0 on first iteration (m = -inf)
      dsum *= r; a0 *= r; a1 *= r; a2 *= r; a3 *= r; a4 *= r; a5 *= r;
      m = mc;
    }
    float wA = __expf(scA - m);   // 0 for inactive
    float wB = __expf(scB - m);
    dsum += wA + wB;
    const unsigned* r2A = (const unsigned*)(x2b + (size_t)seA.x * D);
    const unsigned* r2B = (const unsigned*)(x2b + (size_t)seB.x * D);
    unsigned qA0 = r2A[j], qA1 = r2A[j + 16], qA2 = r2A[j + 32];
    unsigned qB0 = r2B[j], qB1 = r2B[j + 16], qB2 = r2B[j + 32];
    a0 += wA * bflo(qA0) + wB * bflo(qB0);
    a1 += wA * bfhi(qA0) + wB * bfhi(qB0);
    a2 += wA * bflo(qA1) + wB * bflo(qB1);
    a3 += wA * bfhi(qA1) + wB * bfhi(qB1);
    a4 += wA * bflo(qA2) + wB * bflo(qB2);
    a5 += wA * bfhi(qA2) + wB * bfhi(qB2);
  }
  a0 += __shfl_xor(a0, 16); a0 += __shfl_xor(a0, 32);
  a1 += __shfl_xor(a1, 16); a1 += __shfl_xor(a1, 32);
  a2 += __shfl_xor(a2, 16); a2 += __shfl_xor(a2, 32);
  a3 += __shfl_xor(a3, 16); a3 += __shfl_xor(a3, 32);
  a4 += __shfl_xor(a4, 16); a4 += __shfl_xor(a4, 32);
  a5 += __shfl_xor(a5, 16); a5 += __shfl_xor(a5, 32);
  dsum += __shfl_xor(dsum, 16); dsum += __shfl_xor(dsum, 32);
  float inv = 1.0f / (dsum + 1e-16f);
  if (lane < 16){
    size_t o = (size_t)t * D + 2 * j;   // elems 2j,2j+1 / +32 / +64
    node_acc[o]      += a0 * inv;
    node_acc[o + 1]  += a1 * inv;
    node_acc[o + 32] += a2 * inv;
    node_acc[o + 33] += a3 * inv;
    node_acc[o + 64] += a4 * inv;
    node_acc[o + 65] += a5 * inv;
  }
}

// K6: per-graph partial sums (batch sorted; binary-search boundaries). No fence.
__global__ __launch_bounds__(96) void k_pool(
    const float* __restrict__ node_out, const int* __restrict__ batch,
    float* __restrict__ sums, int n){
  int g = blockIdx.x;
  int chunk = blockIdx.y, nch = gridDim.y;
  int lo = lbound(batch, n, g);
  int hi = lbound(batch, n, g + 1);
  int cnt = hi - lo;
  if (cnt <= 0) return;
  int per = (cnt + nch - 1) / nch;
  int b = lo + chunk * per;
  int e = min(b + per, hi);
  if (b >= e) return;
  int d = threadIdx.x;
  float s = 0.0f;
  for (int r = b; r < e; ++r) s += node_out[(size_t)r * D + d];
  atomicAdd(&sums[g * D + d], s);
}

// K7: divide by counts
__global__ __launch_bounds__(256) void k_final(
    const float* __restrict__ sums, const int* __restrict__ batch,
    float* __restrict__ out, int n, int total){
  int i = blockIdx.x * blockDim.x + threadIdx.x;
  if (i >= total) return;
  int g = i / D;
  int lo = lbound(batch, n, g);
  int hi = lbound(batch, n, g + 1);
  float c = (float)((hi - lo) > 1 ? (hi - lo) : 1);
  out[i] = sums[i] / c;
}

extern "C" void kernel_launch(void* const* d_in, const int* in_sizes, int n_in,
                              void* d_out, int out_size, void* d_ws, size_t ws_size,
                              hipStream_t stream){
  const float* x     = (const float*)d_in[0];
  const int*   eidx  = (const int*)d_in[1];
  const float* eattr = (const float*)d_in[2];
  const int*   batch = (const int*)d_in[3];
  const float* w1 = (const float*)d_in[4];
  const float* b1 = (const float*)d_in[5];
  const float* w2 = (const float*)d_in[6];
  const float* b2 = (const float*)d_in[7];
  const float* w3 = (const float*)d_in[8];
  const float* b3 = (const float*)d_in[9];
  const float* w4 = (const float*)d_in[10];
  const float* b4 = (const float*)d_in[11];
  const float* w5 = (const float*)d_in[12];
  const float* b5 = (const float*)d_in[13];
  float* out = (float*)d_out;

  const int N = in_sizes[0] / D;
  const int E = in_sizes[2];
  const int* srcI = eidx;
  const int* dstI = eidx + E;
  const int NB = (N + 255) / 256;

  char* base = (char*)d_ws;
  size_t off = 0;
  auto alloc = [&](size_t bytes) -> char* {
    char* p = base + off;
    off = (off + bytes + 255) & ~(size_t)255;
    return p;
  };
  char* zbase = base;
  int*   deg   = (int*)alloc((size_t)N * 4);
  int*   fill  = (int*)alloc((size_t)N * 4);
  float* sums  = (float*)alloc((size_t)out_size * 4);
  size_t zbytes = off;
  float* node_acc = (float*)alloc((size_t)N * D * 4);
  unsigned short* x2v = (unsigned short*)alloc((size_t)N * D * 2);
  float* x3v      = (float*)alloc((size_t)N * D * 4);
  unsigned short* x4v = (unsigned short*)alloc((size_t)N * D * 2);
  float* p5       = (float*)alloc((size_t)N * 4);
  float* pb       = (float*)alloc((size_t)N * 4);
  int*   rowp     = (int*)alloc((size_t)(N + 1) * 4);
  int*   partials = (int*)alloc((size_t)(NB + 1) * 4);
  int2*  sortedSE = (int2*)alloc((size_t)E * 8);
  unsigned short* wt_h = (unsigned short*)alloc((size_t)4 * D * D * 2);
  unsigned short* wt_l = (unsigned short*)alloc((size_t)4 * D * D * 2);
  (void)ws_size; (void)n_in;

  hipMemsetAsync(zbase, 0, zbytes, stream);

  k_wprep_deg<<<dim3((E + 255) / 256), dim3(256), 0, stream>>>(
      w1, w2, w3, w4, wt_h, wt_l, dstI, deg, E);
  k_transform_mfma<<<dim3((N + 15) / 16), dim3(256), 0, stream>>>(
      x, wt_h, wt_l, b1, b2, b3, b4, w5, b5,
      node_acc, x2v, x3v, x4v, p5, pb, N);
  k_scanA<<<dim3(NB), dim3(256), 0, stream>>>(deg, rowp, partials, N);
  k_scanB<<<dim3(1), dim3(256), 0, stream>>>(partials, rowp, NB, N);
  k_scatter<<<dim3((E + 255) / 256), dim3(256), 0, stream>>>(
      srcI, dstI, eattr, rowp, partials, fill, sortedSE, E);
  k_attn<<<dim3((N + 3) / 4), dim3(256), 0, stream>>>(
      x2v, x3v, x4v, p5, pb, sortedSE, rowp, partials, node_acc, N);
  k_pool<<<dim3(out_size / D, 32), dim3(D), 0, stream>>>(node_acc, batch, sums, N);
  k_final<<<dim3((out_size + 255) / 256), dim3(256), 0, stream>>>(
      sums, batch, out, N, out_size);
}

// Round 10
// 273.191 us; speedup vs baseline: 2.0810x; 1.1064x over previous
//
#include <hip/hip_runtime.h>
#include <math.h>

#define D 96
#define RSQ 0.10206207261596577f  // 1/sqrt(96)
#define TSTRIDE 104               // padded LDS row stride (bf16 elems)

typedef __attribute__((ext_vector_type(8))) short short8;
typedef __attribute__((ext_vector_type(4))) float f32x4;

__device__ __forceinline__ unsigned short f2bf(float f){
  unsigned u = __float_as_uint(f);
  unsigned r = (u + 0x7fff + ((u >> 16) & 1)) >> 16;  // RNE
  return (unsigned short)r;
}
__device__ __forceinline__ float bf2f(unsigned short h){
  return __uint_as_float(((unsigned)h) << 16);
}
__device__ __forceinline__ float bflo(unsigned u){ return __uint_as_float(u << 16); }
__device__ __forceinline__ float bfhi(unsigned u){ return __uint_as_float(u & 0xffff0000u); }
__device__ __forceinline__ int lbound(const int* __restrict__ a, int n, int v){
  int lo = 0, hi = n;
  while (lo < hi){ int mid = (lo + hi) >> 1; if (a[mid] < v) lo = mid + 1; else hi = mid; }
  return lo;
}

// K0: weight prep (transpose + hi/lo bf16 split) + degree histogram, keeping rank[e]
__global__ __launch_bounds__(256) void k_wprep_deg(
    const float* __restrict__ w1, const float* __restrict__ w2,
    const float* __restrict__ w3, const float* __restrict__ w4,
    unsigned short* __restrict__ wt_h, unsigned short* __restrict__ wt_l,
    const int* __restrict__ dstI, int* __restrict__ deg,
    int* __restrict__ rank, int E){
  int gtid = blockIdx.x * 256 + threadIdx.x;
  if (gtid < 4 * D * D){
    int m = gtid / (D * D);
    int r = gtid % (D * D);
    int nn = r / D, k = r % D;
    const float* w = (m == 0) ? w1 : (m == 1) ? w2 : (m == 2) ? w3 : w4;
    float v = w[k * D + nn];
    unsigned short h = f2bf(v);
    wt_h[gtid] = h;
    wt_l[gtid] = f2bf(v - bf2f(h));
  }
  if (gtid < E) rank[gtid] = atomicAdd(&deg[dstI[gtid]], 1);
}

// K1: node transforms via split-bf16 MFMA. Block = 32 nodes, 4 waves; wave wv computes
// x@w_wv for two 16-row halves sharing each B-fragment load (6 MFMA per B-pair).
// x2/x4 written as bf16 interleaved into x24[node][192] = [x4row | x2row]; acc/x3 f32.
// Wave 2 also computes fused p5 = dot(x3,w5), pb = dot(x3,b5).
__global__ __launch_bounds__(256) void k_transform_mfma(
    const float* __restrict__ x,
    const unsigned short* __restrict__ wt_h, const unsigned short* __restrict__ wt_l,
    const float* __restrict__ b1, const float* __restrict__ b2,
    const float* __restrict__ b3, const float* __restrict__ b4,
    const float* __restrict__ w5, const float* __restrict__ b5,
    float* __restrict__ acc_o, unsigned short* __restrict__ x24,
    float* __restrict__ x3o,
    float* __restrict__ p5, float* __restrict__ pb, int n){
  __shared__ __align__(16) unsigned short xs_h[32][TSTRIDE];
  __shared__ __align__(16) unsigned short xs_l[32][TSTRIDE];
  int tid = threadIdx.x;
  int n0 = blockIdx.x * 32;
  for (int e = tid; e < 32 * D; e += 256){
    int r = e / D, c = e % D;
    int node = n0 + r;
    float v = (node < n) ? x[(size_t)node * D + c] : 0.0f;
    unsigned short h = f2bf(v);
    xs_h[r][c] = h;
    xs_l[r][c] = f2bf(v - bf2f(h));
  }
  __syncthreads();

  int wv = tid >> 6;
  int lane = tid & 63;
  int lr = lane & 15;
  int kg = lane >> 4;

  f32x4 c00 = {0,0,0,0}, c01 = {0,0,0,0}, c02 = {0,0,0,0};
  f32x4 c03 = {0,0,0,0}, c04 = {0,0,0,0}, c05 = {0,0,0,0};
  f32x4 c10 = {0,0,0,0}, c11 = {0,0,0,0}, c12 = {0,0,0,0};
  f32x4 c13 = {0,0,0,0}, c14 = {0,0,0,0}, c15 = {0,0,0,0};
  const unsigned short* wtm_h = wt_h + (size_t)wv * D * D;
  const unsigned short* wtm_l = wt_l + (size_t)wv * D * D;

  #pragma unroll
  for (int k0 = 0; k0 < D; k0 += 32){
    int kb = k0 + kg * 8;
    short8 ah0 = *(const short8*)&xs_h[lr][kb];
    short8 al0 = *(const short8*)&xs_l[lr][kb];
    short8 ah1 = *(const short8*)&xs_h[lr + 16][kb];
    short8 al1 = *(const short8*)&xs_l[lr + 16][kb];
    #define NC_BODY(nc, C0, C1) { \
      int col = (nc) * 16 + lr; \
      short8 bh = *(const short8*)(wtm_h + col * D + kb); \
      short8 bl = *(const short8*)(wtm_l + col * D + kb); \
      C0 = __builtin_amdgcn_mfma_f32_16x16x32_bf16(ah0, bh, C0, 0, 0, 0); \
      C0 = __builtin_amdgcn_mfma_f32_16x16x32_bf16(ah0, bl, C0, 0, 0, 0); \
      C0 = __builtin_amdgcn_mfma_f32_16x16x32_bf16(al0, bh, C0, 0, 0, 0); \
      C1 = __builtin_amdgcn_mfma_f32_16x16x32_bf16(ah1, bh, C1, 0, 0, 0); \
      C1 = __builtin_amdgcn_mfma_f32_16x16x32_bf16(ah1, bl, C1, 0, 0, 0); \
      C1 = __builtin_amdgcn_mfma_f32_16x16x32_bf16(al1, bh, C1, 0, 0, 0); }
    NC_BODY(0, c00, c10) NC_BODY(1, c01, c11) NC_BODY(2, c02, c12)
    NC_BODY(3, c03, c13) NC_BODY(4, c04, c14) NC_BODY(5, c05, c15)
    #undef NC_BODY
  }

  const float* bias = (wv == 0) ? b1 : (wv == 1) ? b2 : (wv == 2) ? b3 : b4;
  f32x4 p5a0 = {0,0,0,0}, p5a1 = {0,0,0,0};
  f32x4 pba0 = {0,0,0,0}, pba1 = {0,0,0,0};

  #define EPI_BODY(nc, C0, C1) { \
    int col = (nc) * 16 + lr; \
    float bb = bias[col]; \
    float w5v = w5[col], b5v = b5[col]; \
    _Pragma("unroll") \
    for (int q = 0; q < 4; ++q){ \
      float v0e = C0[q] + bb; \
      float v1e = C1[q] + bb; \
      int row0 = kg * 4 + q, row1 = 16 + kg * 4 + q; \
      if (n0 + row0 < n){ \
        if (wv == 0) acc_o[(size_t)(n0 + row0) * D + col] = v0e; \
        else if (wv == 1) x24[(size_t)(n0 + row0) * 192 + 96 + col] = f2bf(v0e); \
        else if (wv == 2) x3o[(size_t)(n0 + row0) * D + col] = v0e; \
        else x24[(size_t)(n0 + row0) * 192 + col] = f2bf(v0e); \
      } \
      if (n0 + row1 < n){ \
        if (wv == 0) acc_o[(size_t)(n0 + row1) * D + col] = v1e; \
        else if (wv == 1) x24[(size_t)(n0 + row1) * 192 + 96 + col] = f2bf(v1e); \
        else if (wv == 2) x3o[(size_t)(n0 + row1) * D + col] = v1e; \
        else x24[(size_t)(n0 + row1) * 192 + col] = f2bf(v1e); \
      } \
      p5a0[q] += v0e * w5v; pba0[q] += v0e * b5v; \
      p5a1[q] += v1e * w5v; pba1[q] += v1e * b5v; \
    } }
  EPI_BODY(0, c00, c10) EPI_BODY(1, c01, c11) EPI_BODY(2, c02, c12)
  EPI_BODY(3, c03, c13) EPI_BODY(4, c04, c14) EPI_BODY(5, c05, c15)
  #undef EPI_BODY

  if (wv == 2){
    #pragma unroll
    for (int off = 1; off < 16; off <<= 1){
      #pragma unroll
      for (int q = 0; q < 4; ++q){
        p5a0[q] += __shfl_xor(p5a0[q], off); pba0[q] += __shfl_xor(pba0[q], off);
        p5a1[q] += __shfl_xor(p5a1[q], off); pba1[q] += __shfl_xor(pba1[q], off);
      }
    }
    if (lr == 0){
      #pragma unroll
      for (int q = 0; q < 4; ++q){
        int row0 = kg * 4 + q, row1 = 16 + kg * 4 + q;
        if (n0 + row0 < n){ p5[n0 + row0] = p5a0[q]; pb[n0 + row0] = pba0[q]; }
        if (n0 + row1 < n){ p5[n0 + row1] = p5a1[q]; pb[n0 + row1] = pba1[q]; }
      }
    }
  }
}

// K3a: per-block exclusive scan (256 elements/block) + block totals
__global__ __launch_bounds__(256) void k_scanA(
    const int* __restrict__ deg, int* __restrict__ rowp,
    int* __restrict__ partials, int n){
  __shared__ int ws[4];
  int tid = threadIdx.x, lane = tid & 63, wid = tid >> 6;
  int i = blockIdx.x * 256 + tid;
  int v = (i < n) ? deg[i] : 0;
  int s = v;
  #pragma unroll
  for (int off = 1; off < 64; off <<= 1){ int u = __shfl_up(s, off); if (lane >= off) s += u; }
  if (lane == 63) ws[wid] = s;
  __syncthreads();
  if (tid < 4){
    int u = ws[tid];
    #pragma unroll
    for (int off = 1; off < 4; off <<= 1){ int q = __shfl_up(u, off); if (tid >= off) u += q; }
    ws[tid] = u;
  }
  __syncthreads();
  int woff = wid ? ws[wid - 1] : 0;
  if (i < n) rowp[i] = woff + s - v;   // block-local exclusive prefix
  if (tid == 255) partials[blockIdx.x] = ws[3];
}

// K3b: exclusive scan of block totals (in place) + grand total -> rowp[n]
__global__ __launch_bounds__(256) void k_scanB(
    int* __restrict__ partials, int* __restrict__ rowp, int nb, int n){
  __shared__ int ws[4];
  int tid = threadIdx.x, lane = tid & 63, wid = tid >> 6;
  int running = 0;
  for (int base = 0; base < nb; base += 256){
    int i = base + tid;
    int v = (i < nb) ? partials[i] : 0;
    int s = v;
    #pragma unroll
    for (int off = 1; off < 64; off <<= 1){ int u = __shfl_up(s, off); if (lane >= off) s += u; }
    if (lane == 63) ws[wid] = s;
    __syncthreads();
    if (tid < 4){
      int u = ws[tid];
      #pragma unroll
      for (int off = 1; off < 4; off <<= 1){ int q = __shfl_up(u, off); if (tid >= off) u += q; }
      ws[tid] = u;
    }
    __syncthreads();
    int woff = wid ? ws[wid - 1] : 0;
    if (i < nb) partials[i] = running + woff + s - v;
    running += ws[3];
    __syncthreads();
  }
  if (tid == 0) rowp[n] = running;
}

// K4: scatter (src, eattr) into CSR order — atomic-free via precomputed rank
__global__ __launch_bounds__(256) void k_scatter(
    const int* __restrict__ srcI, const int* __restrict__ dstI,
    const float* __restrict__ eattr, const int* __restrict__ rowp,
    const int* __restrict__ partials, const int* __restrict__ rank,
    int2* __restrict__ sortedSE, int E){
  int e = blockIdx.x * blockDim.x + threadIdx.x;
  if (e >= E) return;
  int t = dstI[e];
  int pos = rowp[t] + partials[t >> 8] + rank[e];
  sortedSE[pos] = make_int2(srcI[e], __float_as_int(eattr[e]));
}

// K5: fused attention per dst row — one wave per node, 16 lanes per edge,
// 8 edges in flight; interleaved x24 gathers (one 384B row per edge); online softmax.
__global__ __launch_bounds__(256) void k_attn(
    const unsigned short* __restrict__ x24, const float* __restrict__ x3,
    const float* __restrict__ p5,
    const float* __restrict__ pb, const int2* __restrict__ sortedSE,
    const int* __restrict__ rowp, const int* __restrict__ partials,
    float* __restrict__ node_acc, int n){
  int t = blockIdx.x * 4 + (threadIdx.x >> 6);
  int lane = threadIdx.x & 63;
  if (t >= n) return;
  int beg = rowp[t] + partials[t >> 8];
  int end = (t + 1 < n) ? (rowp[t + 1] + partials[(t + 1) >> 8]) : rowp[n];
  if (beg == end) return;
  int j = lane & 15;
  int g = lane >> 4;

  const float2* r3 = (const float2*)(x3 + (size_t)t * D);
  float2 v0 = r3[j], v1 = r3[j + 16], v2 = r3[j + 32];
  float p5t = p5[t], pbt = pb[t];

  float m = -INFINITY, dsum = 0.0f;
  float a0 = 0, a1 = 0, a2 = 0, a3 = 0, a4 = 0, a5 = 0;

  for (int c = beg; c < end; c += 8){
    int eA = c + g, eB = c + 4 + g;
    bool actA = eA < end, actB = eB < end;
    int2 seA = sortedSE[actA ? eA : end - 1];
    int2 seB = sortedSE[actB ? eB : end - 1];
    const unsigned* rA = (const unsigned*)(x24 + (size_t)seA.x * 192);
    const unsigned* rB = (const unsigned*)(x24 + (size_t)seB.x * 192);
    unsigned uA0 = rA[j], uA1 = rA[j + 16], uA2 = rA[j + 32];
    unsigned uB0 = rB[j], uB1 = rB[j + 16], uB2 = rB[j + 32];
    float sA = v0.x * bflo(uA0) + v0.y * bfhi(uA0)
             + v1.x * bflo(uA1) + v1.y * bfhi(uA1)
             + v2.x * bflo(uA2) + v2.y * bfhi(uA2);
    float sB = v0.x * bflo(uB0) + v0.y * bfhi(uB0)
             + v1.x * bflo(uB1) + v1.y * bfhi(uB1)
             + v2.x * bflo(uB2) + v2.y * bfhi(uB2);
    sA += __shfl_xor(sA, 1); sA += __shfl_xor(sA, 2);
    sA += __shfl_xor(sA, 4); sA += __shfl_xor(sA, 8);
    sB += __shfl_xor(sB, 1); sB += __shfl_xor(sB, 2);
    sB += __shfl_xor(sB, 4); sB += __shfl_xor(sB, 8);
    float scA = actA ? (sA + __int_as_float(seA.y) * p5t + pbt) * RSQ : -INFINITY;
    float scB = actB ? (sB + __int_as_float(seB.y) * p5t + pbt) * RSQ : -INFINITY;
    float mc = fmaxf(scA, scB);
    mc = fmaxf(mc, __shfl_xor(mc, 16));
    mc = fmaxf(mc, __shfl_xor(mc, 32));
    if (mc > m){
      float r = __expf(m - mc);   // 0 on first iteration (m = -inf)
      dsum *= r; a0 *= r; a1 *= r; a2 *= r; a3 *= r; a4 *= r; a5 *= r;
      m = mc;
    }
    float wA = __expf(scA - m);   // 0 for inactive
    float wB = __expf(scB - m);
    dsum += wA + wB;
    unsigned qA0 = rA[48 + j], qA1 = rA[48 + j + 16], qA2 = rA[48 + j + 32];
    unsigned qB0 = rB[48 + j], qB1 = rB[48 + j + 16], qB2 = rB[48 + j + 32];
    a0 += wA * bflo(qA0) + wB * bflo(qB0);
    a1 += wA * bfhi(qA0) + wB * bfhi(qB0);
    a2 += wA * bflo(qA1) + wB * bflo(qB1);
    a3 += wA * bfhi(qA1) + wB * bfhi(qB1);
    a4 += wA * bflo(qA2) + wB * bflo(qB2);
    a5 += wA * bfhi(qA2) + wB * bfhi(qB2);
  }
  a0 += __shfl_xor(a0, 16); a0 += __shfl_xor(a0, 32);
  a1 += __shfl_xor(a1, 16); a1 += __shfl_xor(a1, 32);
  a2 += __shfl_xor(a2, 16); a2 += __shfl_xor(a2, 32);
  a3 += __shfl_xor(a3, 16); a3 += __shfl_xor(a3, 32);
  a4 += __shfl_xor(a4, 16); a4 += __shfl_xor(a4, 32);
  a5 += __shfl_xor(a5, 16); a5 += __shfl_xor(a5, 32);
  dsum += __shfl_xor(dsum, 16); dsum += __shfl_xor(dsum, 32);
  float inv = 1.0f / (dsum + 1e-16f);
  if (lane < 16){
    size_t o = (size_t)t * D + 2 * j;   // elems 2j,2j+1 / +32 / +64
    node_acc[o]      += a0 * inv;
    node_acc[o + 1]  += a1 * inv;
    node_acc[o + 32] += a2 * inv;
    node_acc[o + 33] += a3 * inv;
    node_acc[o + 64] += a4 * inv;
    node_acc[o + 65] += a5 * inv;
  }
}

// K6: per-graph partial sums (batch sorted; binary-search boundaries). No fence.
__global__ __launch_bounds__(96) void k_pool(
    const float* __restrict__ node_out, const int* __restrict__ batch,
    float* __restrict__ sums, int n){
  int g = blockIdx.x;
  int chunk = blockIdx.y, nch = gridDim.y;
  int lo = lbound(batch, n, g);
  int hi = lbound(batch, n, g + 1);
  int cnt = hi - lo;
  if (cnt <= 0) return;
  int per = (cnt + nch - 1) / nch;
  int b = lo + chunk * per;
  int e = min(b + per, hi);
  if (b >= e) return;
  int d = threadIdx.x;
  float s = 0.0f;
  for (int r = b; r < e; ++r) s += node_out[(size_t)r * D + d];
  atomicAdd(&sums[g * D + d], s);
}

// K7: divide by counts
__global__ __launch_bounds__(256) void k_final(
    const float* __restrict__ sums, const int* __restrict__ batch,
    float* __restrict__ out, int n, int total){
  int i = blockIdx.x * blockDim.x + threadIdx.x;
  if (i >= total) return;
  int g = i / D;
  int lo = lbound(batch, n, g);
  int hi = lbound(batch, n, g + 1);
  float c = (float)((hi - lo) > 1 ? (hi - lo) : 1);
  out[i] = sums[i] / c;
}

extern "C" void kernel_launch(void* const* d_in, const int* in_sizes, int n_in,
                              void* d_out, int out_size, void* d_ws, size_t ws_size,
                              hipStream_t stream){
  const float* x     = (const float*)d_in[0];
  const int*   eidx  = (const int*)d_in[1];
  const float* eattr = (const float*)d_in[2];
  const int*   batch = (const int*)d_in[3];
  const float* w1 = (const float*)d_in[4];
  const float* b1 = (const float*)d_in[5];
  const float* w2 = (const float*)d_in[6];
  const float* b2 = (const float*)d_in[7];
  const float* w3 = (const float*)d_in[8];
  const float* b3 = (const float*)d_in[9];
  const float* w4 = (const float*)d_in[10];
  const float* b4 = (const float*)d_in[11];
  const float* w5 = (const float*)d_in[12];
  const float* b5 = (const float*)d_in[13];
  float* out = (float*)d_out;

  const int N = in_sizes[0] / D;
  const int E = in_sizes[2];
  const int* srcI = eidx;
  const int* dstI = eidx + E;
  const int NB = (N + 255) / 256;
  const int NT = (N + 31) / 32;

  char* base = (char*)d_ws;
  size_t off = 0;
  auto alloc = [&](size_t bytes) -> char* {
    char* p = base + off;
    off = (off + bytes + 255) & ~(size_t)255;
    return p;
  };
  char* zbase = base;
  int*   deg   = (int*)alloc((size_t)N * 4);
  float* sums  = (float*)alloc((size_t)out_size * 4);
  size_t zbytes = off;
  float* node_acc = (float*)alloc((size_t)N * D * 4);
  unsigned short* x24 = (unsigned short*)alloc((size_t)N * 192 * 2);
  float* x3v      = (float*)alloc((size_t)N * D * 4);
  float* p5       = (float*)alloc((size_t)N * 4);
  float* pb       = (float*)alloc((size_t)N * 4);
  int*   rowp     = (int*)alloc((size_t)(N + 1) * 4);
  int*   partials = (int*)alloc((size_t)(NB + 1) * 4);
  int*   rank     = (int*)alloc((size_t)E * 4);
  int2*  sortedSE = (int2*)alloc((size_t)E * 8);
  unsigned short* wt_h = (unsigned short*)alloc((size_t)4 * D * D * 2);
  unsigned short* wt_l = (unsigned short*)alloc((size_t)4 * D * D * 2);
  (void)ws_size; (void)n_in;

  hipMemsetAsync(zbase, 0, zbytes, stream);

  k_wprep_deg<<<dim3((E + 255) / 256), dim3(256), 0, stream>>>(
      w1, w2, w3, w4, wt_h, wt_l, dstI, deg, rank, E);
  k_transform_mfma<<<dim3(NT), dim3(256), 0, stream>>>(
      x, wt_h, wt_l, b1, b2, b3, b4, w5, b5,
      node_acc, x24, x3v, p5, pb, N);
  k_scanA<<<dim3(NB), dim3(256), 0, stream>>>(deg, rowp, partials, N);
  k_scanB<<<dim3(1), dim3(256), 0, stream>>>(partials, rowp, NB, N);
  k_scatter<<<dim3((E + 255) / 256), dim3(256), 0, stream>>>(
      srcI, dstI, eattr, rowp, partials, rank, sortedSE, E);
  k_attn<<<dim3((N + 3) / 4), dim3(256), 0, stream>>>(
      x24, x3v, p5, pb, sortedSE, rowp, partials, node_acc, N);
  k_pool<<<dim3(out_size / D, 32), dim3(D), 0, stream>>>(node_acc, batch, sums, N);
  k_final<<<dim3((out_size + 255) / 256), dim3(256), 0, stream>>>(
      sums, batch, out, N, out_size);
}